// Round 5
// baseline (13359.163 us; speedup 1.0000x reference)
//
#include <hip/hip_runtime.h>
#include <math.h>

// ---------------- problem constants ----------------
// B=2, S=240, WIDTH=128, M=20, PAD=16 -> padded spatial 256x256
// modes: kx in {0..19} (w1) and {236..255} (w2) -> j=0..39 ; ky in {0..19}

// ---------------- ws layout (float offsets) ----------------
#define SZ_H   (2ull*256*256*128)          // 8,388,608 floats
#define O_HA   0ull
#define O_HB   (O_HA + SZ_H)
#define O_G    (O_HB + SZ_H)               // float2[2*256*20*128]
#define SZ_G   (2ull*256*20*128*2)
#define O_FTT  (O_G + SZ_G)                // float2[128*2*800]
#define SZ_FT  (2ull*40*20*128*2)
#define O_OFT  (O_FTT + SZ_FT)
#define O_EY   (O_OFT + SZ_FT)             // float2[256*20]
#define SZ_EY  (256ull*20*2)
#define O_EX   (O_EY + SZ_EY)              // float2[256*40]
#define SZ_EX  (256ull*40*2)
#define O_EXI  (O_EX + SZ_EX)
#define O_WWT  (O_EXI + SZ_EX)             // 5*128*128 transposed w_w
#define SZ_WWT 81920ull
#define O_PART (O_WWT + SZ_WWT)            // 8 x 204800 float2 partials
#define SZ_PART (8ull*204800*2)

// branchless gelu: erf via Abramowitz-Stegun 7.1.26 (|err| <= 1.5e-7)
static __device__ __forceinline__ float gelu_f(float v) {
    float z  = v * 0.70710678118654752f;
    float az = fabsf(z);
    float t  = __builtin_amdgcn_rcpf(fmaf(0.3275911f, az, 1.0f));
    float p  = fmaf(fmaf(fmaf(fmaf(1.061405429f, t, -1.453152027f), t,
                    1.421413741f), t, -0.284496736f), t, 0.254829592f);
    float e  = __expf(-z * z);
    float er = fmaf(-p * t, e, 1.0f);      // erf(|z|)
    er = copysignf(er, z);
    return 0.5f * v * (1.0f + er);
}

// ---------------- K0: tables + w_w transpose ----------------
__global__ void k_prep(const float* __restrict__ w_w, float* __restrict__ ws) {
    int i = blockIdx.x * 256 + threadIdx.x;
    const float STEP = 6.2831853071795864769f / 256.0f;
    if (i < 5120) {                       // Ey[y][ky] = exp(-2pi i ky y/256)
        int ky = i % 20, y = i / 20;
        int t = (ky * y) & 255;
        float th = t * STEP;
        ws[O_EY + 2*(size_t)i]     = cosf(th);
        ws[O_EY + 2*(size_t)i + 1] = -sinf(th);
    } else if (i < 15360) {               // Ex[x][j] = exp(-2pi i kx x/256)
        int m = i - 5120; int j = m % 40, x = m / 40;
        int kx = (j < 20) ? j : (216 + j);
        int t = (kx * x) & 255;
        float th = t * STEP;
        ws[O_EX + 2*(size_t)m]     = cosf(th);
        ws[O_EX + 2*(size_t)m + 1] = -sinf(th);
    } else if (i < 25600) {               // Exi[x][j] = exp(+2pi i kx x/256)
        int m = i - 15360; int j = m % 40, x = m / 40;
        int kx = (j < 20) ? j : (216 + j);
        int t = (kx * x) & 255;
        float th = t * STEP;
        ws[O_EXI + 2*(size_t)m]     = cosf(th);
        ws[O_EXI + 2*(size_t)m + 1] = sinf(th);
    } else {                              // wwT[l][ic][oc] = w_w[l][oc][ic]
        int m = i - 25600;
        if (m < 81920) {
            int l = m >> 14, r = m & 16383;
            int ic = r >> 7, oc = r & 127;
            ws[O_WWT + m] = w_w[(size_t)l*16384 + oc*128 + ic];
        }
    }
}

// ---------------- K1: fc0 + grid concat + zero-pad (float4) -----------
__global__ __launch_bounds__(256) void k_fc0(const float* __restrict__ xin,
        const float* __restrict__ w, const float* __restrict__ bv,
        float4* __restrict__ H4) {
    size_t e = (size_t)blockIdx.x * 256 + threadIdx.x;   // < 4,194,304
    int c4 = (int)(e & 31) * 4;
    int y = (int)((e >> 5) & 255);
    int x = (int)((e >> 13) & 255);
    int b = (int)(e >> 21);
    float4 h = make_float4(0.f, 0.f, 0.f, 0.f);
    if (x < 240 && y < 240) {
        const float* xp = xin + (((size_t)(b*240 + x))*240 + y)*3;
        float x0 = xp[0], x1 = xp[1], x2 = xp[2];
        float gx = x*(1.0f/239.0f), gy = y*(1.0f/239.0f);
        float4 w0 = *(const float4*)&w[c4];
        float4 w1 = *(const float4*)&w[128 + c4];
        float4 w2 = *(const float4*)&w[256 + c4];
        float4 w3 = *(const float4*)&w[384 + c4];
        float4 w4 = *(const float4*)&w[512 + c4];
        float4 bb = *(const float4*)&bv[c4];
        h.x = bb.x + x0*w0.x + x1*w1.x + x2*w2.x + gx*w3.x + gy*w4.x;
        h.y = bb.y + x0*w0.y + x1*w1.y + x2*w2.y + gx*w3.y + gy*w4.y;
        h.z = bb.z + x0*w0.z + x1*w1.z + x2*w2.z + gx*w3.z + gy*w4.z;
        h.w = bb.w + x0*w0.w + x1*w1.w + x2*w2.w + gx*w3.w + gy*w4.w;
    }
    H4[e] = h;
}

// ---------------- K2: y-DFT  H -> G[b][x][ky][c] ----------------
// grid 1024 = b(2) x x(256) x kh(2): ky split over blocks -> 16 waves/CU
__global__ __launch_bounds__(256) void k_ydft(const float* __restrict__ H,
        const float* __restrict__ Ey, float2* __restrict__ G) {
    int kh = blockIdx.x & 1;
    int x  = (blockIdx.x >> 1) & 255;
    int b  = blockIdx.x >> 9;
    int c = threadIdx.x & 127;
    int yq = __builtin_amdgcn_readfirstlane((int)(threadIdx.x >> 7));  // 0,1
    int k0 = kh * 10;
    const float* Hrow = H + ((size_t)(b*256 + x)) * 256 * 128;
    float ar[10], ai[10];
    #pragma unroll
    for (int k = 0; k < 10; k++) { ar[k] = 0.f; ai[k] = 0.f; }
    #pragma unroll 2
    for (int i = 0; i < 128; i++) {
        int y = yq*128 + i;
        float v = Hrow[(size_t)y*128 + c];
        const float* e = Ey + (size_t)y*40 + k0*2;
        #pragma unroll
        for (int k = 0; k < 10; k++) {
            ar[k] = fmaf(v, e[2*k],   ar[k]);
            ai[k] = fmaf(v, e[2*k+1], ai[k]);
        }
    }
    __shared__ float red[10][128][2];   // 10 KB
    if (yq == 1) {
        #pragma unroll
        for (int k = 0; k < 10; k++) { red[k][c][0] = ar[k]; red[k][c][1] = ai[k]; }
    }
    __syncthreads();
    if (yq == 0) {
        float2* Gp = G + ((size_t)(b*256 + x))*20*128;
        #pragma unroll
        for (int k = 0; k < 10; k++)
            Gp[(k0 + k)*128 + c] = make_float2(ar[k] + red[k][c][0], ai[k] + red[k][c][1]);
    }
}

// ---------------- K3: x-DFT  G -> ftT[ic][b][j*20+ky] ----------------
// 640 blocks. block 256 = xq(8) x cl(32). shfl_xor(32) + 3-slot LDS combine.
__global__ __launch_bounds__(256) void k_xdft(const float2* __restrict__ G,
        const float* __restrict__ Ex, float2* __restrict__ ftT) {
    // grid 640 = ch(4) x jq(4) x ky(20) x b(2)
    int t = blockIdx.x;
    int ch = t & 3, jq = (t >> 2) & 3, ky = (t >> 4) % 20, b = t / 320;
    int cl = threadIdx.x & 31;
    int xq = threadIdx.x >> 5;            // 0..7 (half-wave granularity)
    int c = ch*32 + cl;
    int j0 = jq*10;
    float ar[10], ai[10];
    #pragma unroll
    for (int k = 0; k < 10; k++) { ar[k] = 0.f; ai[k] = 0.f; }
    for (int i = 0; i < 32; i++) {
        int x = xq*32 + i;
        float2 g = G[(((size_t)(b*256 + x))*20 + ky)*128 + c];
        const float2* e2 = (const float2*)(Ex + (size_t)x*80) + j0;
        #pragma unroll
        for (int k = 0; k < 10; k++) {
            float2 e = e2[k];
            ar[k] = fmaf(g.x, e.x, fmaf(-g.y, e.y, ar[k]));
            ai[k] = fmaf(g.x, e.y, fmaf( g.y, e.x, ai[k]));
        }
    }
    // merge xq pairs across half-waves
    #pragma unroll
    for (int k = 0; k < 10; k++) {
        ar[k] += __shfl_xor(ar[k], 32);
        ai[k] += __shfl_xor(ai[k], 32);
    }
    __shared__ float red[3][10][32][2];   // 7.5 KB
    int wid = threadIdx.x >> 6;           // wave 0..3
    int sub = threadIdx.x & 63;
    if (wid > 0 && sub < 32) {
        #pragma unroll
        for (int k = 0; k < 10; k++) { red[wid-1][k][cl][0] = ar[k]; red[wid-1][k][cl][1] = ai[k]; }
    }
    __syncthreads();
    if (wid == 0 && sub < 32) {
        #pragma unroll
        for (int k = 0; k < 10; k++) {
            float rr = ar[k], ii = ai[k];
            #pragma unroll
            for (int q = 0; q < 3; q++) { rr += red[q][k][cl][0]; ii += red[q][k][cl][1]; }
            ftT[((size_t)c*2 + b)*800 + (size_t)(j0 + k)*20 + ky] = make_float2(rr, ii);
        }
    }
}

// ---------------- K4: mode mixing (HBM-heavy einsum, ic-splittable) ----
__global__ __launch_bounds__(448) void k_modemix(const float2* __restrict__ w1,
        const float2* __restrict__ w2, const float2* __restrict__ ftT,
        float2* __restrict__ outp, int ic_per) {
    int bid = blockIdx.x & 255;
    int icq = blockIdx.x >> 8;             // 0 when unsplit
    int oc = bid >> 1;
    int mh = bid & 1;
    int tid = threadIdx.x;
    if (tid >= 400) return;
    int wsel = tid / 200;
    int m = mh*200 + (tid % 200);
    int jk = wsel*400 + m;
    const float2* wb = wsel ? w2 : w1;
    int ic0 = icq * ic_per;
    float ar0=0.f, ai0=0.f, ar1=0.f, ai1=0.f;
    #pragma unroll 8
    for (int i = 0; i < ic_per; i++) {
        int ic = ic0 + i;
        float2 wv = wb[((size_t)(ic*128 + oc))*400 + m];
        float2 f0 = ftT[(size_t)ic*1600 + jk];
        float2 f1 = ftT[(size_t)ic*1600 + 800 + jk];
        ar0 = fmaf(f0.x, wv.x, fmaf(-f0.y, wv.y, ar0));
        ai0 = fmaf(f0.x, wv.y, fmaf( f0.y, wv.x, ai0));
        ar1 = fmaf(f1.x, wv.x, fmaf(-f1.y, wv.y, ar1));
        ai1 = fmaf(f1.x, wv.y, fmaf( f1.y, wv.x, ai1));
    }
    float2* o = outp + (size_t)icq * 204800;
    o[(size_t)jk*128 + oc]         = make_float2(ar0, ai0);
    o[(size_t)(800 + jk)*128 + oc] = make_float2(ar1, ai1);
}

// reduce 8 partials -> oft
__global__ __launch_bounds__(512) void k_modered(const float2* __restrict__ part,
        float2* __restrict__ oft) {
    int i = blockIdx.x * 512 + threadIdx.x;
    if (i >= 204800) return;
    float2 s = part[i];
    #pragma unroll
    for (int q = 1; q < 8; q++) {
        float2 p = part[(size_t)q*204800 + i];
        s.x += p.x; s.y += p.y;
    }
    oft[i] = s;
}

// ---------------- K5: x-IDFT  oft -> T[b][x][ky][oc] (into G buffer) ---
// grid 1024 = b(2) x x(256) x kh(2); block 256 = js(2) x oc(128).
__global__ __launch_bounds__(256) void k_xidft(const float2* __restrict__ oft,
        const float* __restrict__ Exi, float2* __restrict__ T) {
    int kh = blockIdx.x & 1;
    int x  = (blockIdx.x >> 1) & 255;
    int b  = blockIdx.x >> 9;
    int oc = threadIdx.x & 127;
    int js = __builtin_amdgcn_readfirstlane((int)(threadIdx.x >> 7));  // 0,1
    int k0 = kh * 10;
    float ar[10], ai[10];
    #pragma unroll
    for (int k = 0; k < 10; k++) { ar[k] = 0.f; ai[k] = 0.f; }
    const float2* ob = oft + (size_t)b*800*128;
    for (int j = js*20; j < js*20 + 20; j++) {
        float er = Exi[(size_t)x*80 + 2*j], ei = Exi[(size_t)x*80 + 2*j + 1];
        #pragma unroll
        for (int k = 0; k < 10; k++) {
            float2 o = ob[(size_t)(j*20 + k0 + k)*128 + oc];
            ar[k] = fmaf(o.x, er, fmaf(-o.y, ei, ar[k]));
            ai[k] = fmaf(o.x, ei, fmaf( o.y, er, ai[k]));
        }
    }
    __shared__ float red[10][128][2];   // 10 KB
    if (js == 1) {
        #pragma unroll
        for (int k = 0; k < 10; k++) { red[k][oc][0] = ar[k]; red[k][oc][1] = ai[k]; }
    }
    __syncthreads();
    if (js == 0) {
        float2* Tp = T + ((size_t)(b*256 + x))*20*128;
        #pragma unroll
        for (int k = 0; k < 10; k++)
            Tp[(k0 + k)*128 + oc] = make_float2(ar[k] + red[k][oc][0], ai[k] + red[k][oc][1]);
    }
}

// -------- K6: y-IDFT + pointwise linear + bias + gelu ------------------
// R2 geometry (2048 x 256, 64-y tile) + LDS-staged wwT chunks:
// per-wave private dbuf (global->VGPR issue-early, ds_write late, uniform
// ds_read_b128 consume) removes the s_load SGPR-prefetch ceiling.
__global__ __launch_bounds__(256, 3) void k_spec_lin(const float* __restrict__ H,
        const float2* __restrict__ T, const float* __restrict__ wwT,
        const float* __restrict__ wb, float* __restrict__ Hout, int do_gelu) {
    // grid 2048 = ((b*256)+x)*4 + yg
    int yg = blockIdx.x & 3;
    int x  = (blockIdx.x >> 2) & 255;
    int b  = blockIdx.x >> 10;
    int tid = threadIdx.x;
    int lane = tid & 63;
    int wv = __builtin_amdgcn_readfirstlane(tid >> 6);   // 0..3
    int oc0 = wv * 32;
    int y0 = yg * 64;
    __shared__ __align__(16) float hl[64][132];    // 33.8 KB
    __shared__ __align__(16) float wbuf[4][2][512]; // 16 KB (per-wave dbuf)
    const float* Hbase = H + (((size_t)(b*256 + x))*256 + y0)*128;
    #pragma unroll
    for (int it = 0; it < 8; it++) {
        int i = tid + it*256;                // 2048 float4
        int pi = i >> 5, c4 = (i & 31)*4;
        float4 v = *(const float4*)&Hbase[(size_t)pi*128 + c4];
        *(float4*)&hl[pi][c4] = v;
    }
    __syncthreads();
    float acc[32];
    #pragma unroll
    for (int o = 0; o < 32; o++) acc[o] = 0.f;
    // linear: 8 chunks of 16 ic; weights staged via per-wave LDS dbuf
    int wr0 = (lane >> 3)*128 + (lane & 7)*4;      // global offsets
    int wr1 = wr0 + 8*128;
    int ws0 = (lane >> 3)*32 + (lane & 7)*4;       // LDS offsets
    int ws1 = ws0 + 8*32;
    float4 pA, pB;
    {
        const float* src = &wwT[oc0];
        pA = *(const float4*)&src[wr0];
        pB = *(const float4*)&src[wr1];
    }
    #pragma unroll 2
    for (int cb = 0; cb < 8; cb++) {
        float* wbp = &wbuf[wv][cb & 1][0];
        *(float4*)&wbp[ws0] = pA;
        *(float4*)&wbp[ws1] = pB;
        if (cb < 7) {
            const float* src = &wwT[(size_t)((cb + 1)*16)*128 + oc0];
            pA = *(const float4*)&src[wr0];
            pB = *(const float4*)&src[wr1];
        }
        float tvals[16];
        #pragma unroll
        for (int q = 0; q < 4; q++)
            *(float4*)&tvals[q*4] = *(const float4*)&hl[lane][cb*16 + q*4];
        #pragma unroll
        for (int ii = 0; ii < 16; ii++) {
            float t = tvals[ii];
            #pragma unroll
            for (int o4 = 0; o4 < 8; o4++) {
                float4 w = *(const float4*)&wbp[ii*32 + o4*4];
                acc[o4*4]   = fmaf(t, w.x, acc[o4*4]);
                acc[o4*4+1] = fmaf(t, w.y, acc[o4*4+1]);
                acc[o4*4+2] = fmaf(t, w.z, acc[o4*4+2]);
                acc[o4*4+3] = fmaf(t, w.w, acc[o4*4+3]);
            }
        }
    }
    // per-lane trig (f(ky)/65536 folded in) — after linear (live-range)
    float csr[20], csi[20];
    {
        int y = y0 + lane;
        #pragma unroll
        for (int k = 0; k < 20; k++) {
            int t = (k * y) & 255;
            float th = t * (6.2831853071795864769f/256.0f);
            float f = (k == 0 ? 1.0f : 2.0f) * (1.0f/65536.0f);
            csr[k] = f * __cosf(th);
            csi[k] = f * __sinf(th);
        }
    }
    // spectral: T values wave-uniform (s_load), trig lane-varying
    const float2* Tp = T + ((size_t)(b*256 + x))*20*128 + oc0;
    for (int k = 0; k < 20; k++) {
        const float2* tr = Tp + (size_t)k*128;
        float cr = csr[k], ci = csi[k];
        #pragma unroll
        for (int o = 0; o < 32; o++) {
            float2 tv = tr[o];
            acc[o] = fmaf(tv.x, cr, fmaf(-tv.y, ci, acc[o]));
        }
    }
    __syncthreads();            // all hl reads complete
    const float* bp = &wb[oc0];
    #pragma unroll
    for (int o4 = 0; o4 < 8; o4++) {
        float4 r;
        r.x = acc[o4*4]   + bp[o4*4];
        r.y = acc[o4*4+1] + bp[o4*4+1];
        r.z = acc[o4*4+2] + bp[o4*4+2];
        r.w = acc[o4*4+3] + bp[o4*4+3];
        if (do_gelu) { r.x = gelu_f(r.x); r.y = gelu_f(r.y); r.z = gelu_f(r.z); r.w = gelu_f(r.w); }
        *(float4*)&hl[lane][oc0 + o4*4] = r;   // transpose through LDS
    }
    __syncthreads();
    float* Obase = Hout + (((size_t)(b*256 + x))*256 + y0)*128;
    #pragma unroll
    for (int it = 0; it < 32; it++) {
        int i = tid + it*256;   // 8192 floats
        int pi = i >> 7, c = i & 127;
        Obase[(size_t)pi*128 + c] = hl[pi][c];
    }
}

// ---------------- K7: fused crop + fc1 + gelu + heads ------------------
// 64 px/block, 256 thr = 4 waves. Acts in [64][132] LDS (reused h -> t);
// weights via per-wave LDS-staged dbuf chunks (no s_load ceiling).
// phase2: wave -> 32 oc, lane -> px. phase3: wave -> head, lane -> px.
__global__ __launch_bounds__(256, 3) void k_tail(const float* __restrict__ H,
        const float* __restrict__ fc1_w, const float* __restrict__ fc1_b,
        const float* __restrict__ h1w, const float* __restrict__ h1b,
        const float* __restrict__ h2w, const float* __restrict__ h2b,
        float* __restrict__ out) {
    int tid = threadIdx.x;
    int lane = tid & 63;
    int wv = __builtin_amdgcn_readfirstlane(tid >> 6);   // 0..3
    int p0 = blockIdx.x * 64;              // 1800 blocks, 64 px each
    __shared__ __align__(16) float hl[64][132];     // 33.8 KB
    __shared__ __align__(16) float wbuf[4][2][512]; // 16 KB
    // ---- phase 1: load + crop 64 px x 128 c ----
    #pragma unroll
    for (int it = 0; it < 8; it++) {
        int i = tid + it*256;              // 2048 float4
        int pi = i >> 5, c4 = (i & 31)*4;
        int p = p0 + pi;
        int bb = p / 57600, r = p % 57600;
        int xx = r / 240, yy = r % 240;
        float4 v = *(const float4*)&H[(((size_t)(bb*256 + xx))*256 + yy)*128 + c4];
        *(float4*)&hl[pi][c4] = v;
    }
    __syncthreads();
    // ---- phase 2: fc1. wave -> 32-oc slice; lane -> px. staged chunks ----
    int oc0 = wv * 32;
    float acc[32];
    #pragma unroll
    for (int o = 0; o < 32; o++) acc[o] = 0.f;
    {
        int wr0 = (lane >> 3)*128 + (lane & 7)*4;
        int wr1 = wr0 + 8*128;
        int ws0 = (lane >> 3)*32 + (lane & 7)*4;
        int ws1 = ws0 + 8*32;
        float4 pA, pB;
        {
            const float* src = &fc1_w[oc0];
            pA = *(const float4*)&src[wr0];
            pB = *(const float4*)&src[wr1];
        }
        #pragma unroll 2
        for (int cb = 0; cb < 8; cb++) {
            float* wbp = &wbuf[wv][cb & 1][0];
            *(float4*)&wbp[ws0] = pA;
            *(float4*)&wbp[ws1] = pB;
            if (cb < 7) {
                const float* src = &fc1_w[(size_t)((cb + 1)*16)*128 + oc0];
                pA = *(const float4*)&src[wr0];
                pB = *(const float4*)&src[wr1];
            }
            float tvals[16];
            #pragma unroll
            for (int q = 0; q < 4; q++)
                *(float4*)&tvals[q*4] = *(const float4*)&hl[lane][cb*16 + q*4];
            #pragma unroll
            for (int ii = 0; ii < 16; ii++) {
                float t = tvals[ii];
                #pragma unroll
                for (int o4 = 0; o4 < 8; o4++) {
                    float4 w = *(const float4*)&wbp[ii*32 + o4*4];
                    acc[o4*4]   = fmaf(t, w.x, acc[o4*4]);
                    acc[o4*4+1] = fmaf(t, w.y, acc[o4*4+1]);
                    acc[o4*4+2] = fmaf(t, w.z, acc[o4*4+2]);
                    acc[o4*4+3] = fmaf(t, w.w, acc[o4*4+3]);
                }
            }
        }
    }
    __syncthreads();                       // all hl reads done before overwrite
    #pragma unroll
    for (int o4 = 0; o4 < 8; o4++) {
        float4 b4 = *(const float4*)&fc1_b[oc0 + o4*4];
        float4 r;
        r.x = gelu_f(acc[o4*4]   + b4.x);
        r.y = gelu_f(acc[o4*4+1] + b4.y);
        r.z = gelu_f(acc[o4*4+2] + b4.z);
        r.w = gelu_f(acc[o4*4+3] + b4.w);
        *(float4*)&hl[lane][oc0 + o4*4] = r;   // tl[px][oc]
    }
    __syncthreads();
    // ---- phase 3: heads. wave -> head; lane -> px; 16 staged chunks of 8c ----
    int hk = wv;
    float a2[64];
    #pragma unroll
    for (int d = 0; d < 64; d++) a2[d] = 0.f;
    {
        int wr0 = (lane >> 4)*64 + (lane & 15)*4;
        int wr1 = wr0 + 4*64;
        float4 pA, pB;
        const float* hw = h1w + (size_t)hk*8192;
        {
            pA = *(const float4*)&hw[wr0];
            pB = *(const float4*)&hw[wr1];
        }
        #pragma unroll 2
        for (int cb = 0; cb < 16; cb++) {
            float* wbp = &wbuf[wv][cb & 1][0];
            *(float4*)&wbp[wr0] = pA;
            *(float4*)&wbp[wr1] = pB;
            if (cb < 15) {
                const float* src = &hw[(size_t)((cb + 1)*8)*64];
                pA = *(const float4*)&src[wr0];
                pB = *(const float4*)&src[wr1];
            }
            float tv[8];
            *(float4*)&tv[0] = *(const float4*)&hl[lane][cb*8];
            *(float4*)&tv[4] = *(const float4*)&hl[lane][cb*8 + 4];
            #pragma unroll
            for (int cc = 0; cc < 8; cc++) {
                float t = tv[cc];
                #pragma unroll
                for (int d4 = 0; d4 < 16; d4++) {
                    float4 w = *(const float4*)&wbp[cc*64 + d4*4];
                    a2[d4*4]   = fmaf(t, w.x, a2[d4*4]);
                    a2[d4*4+1] = fmaf(t, w.y, a2[d4*4+1]);
                    a2[d4*4+2] = fmaf(t, w.z, a2[d4*4+2]);
                    a2[d4*4+3] = fmaf(t, w.w, a2[d4*4+3]);
                }
            }
        }
    }
    float s = 0.f;
    const float* b1 = &h1b[hk*64];
    const float* w2 = &h2w[hk*64];
    #pragma unroll
    for (int d = 0; d < 64; d++)
        s += gelu_f(a2[d] + b1[d]) * w2[d];
    out[(size_t)hk*115200 + p0 + lane] = s + h2b[hk];
}

// ---------------- launcher ----------------
extern "C" void kernel_launch(void* const* d_in, const int* in_sizes, int n_in,
                              void* d_out, int out_size, void* d_ws, size_t ws_size,
                              hipStream_t stream) {
    const float* x       = (const float*)d_in[0];
    const float* fc0_w   = (const float*)d_in[1];
    const float* fc0_b   = (const float*)d_in[2];
    const float* spec_w1 = (const float*)d_in[3];
    const float* spec_w2 = (const float*)d_in[4];
    const float* w_w     = (const float*)d_in[5];
    const float* w_b     = (const float*)d_in[6];
    const float* fc1_w   = (const float*)d_in[7];
    const float* fc1_b   = (const float*)d_in[8];
    const float* head1_w = (const float*)d_in[9];
    const float* head1_b = (const float*)d_in[10];
    const float* head2_w = (const float*)d_in[11];
    const float* head2_b = (const float*)d_in[12];
    float* ws = (float*)d_ws;
    float* out = (float*)d_out;

    int split = ws_size >= (size_t)(O_PART + SZ_PART) * 4 ? 1 : 0;

    k_prep<<<420, 256, 0, stream>>>(w_w, ws);
    k_fc0<<<16384, 256, 0, stream>>>(x, fc0_w, fc0_b, (float4*)(ws + O_HA));

    float* cur = ws + O_HA;
    float* nxt = ws + O_HB;
    float2* G    = (float2*)(ws + O_G);
    float2* ftT  = (float2*)(ws + O_FTT);
    float2* oft  = (float2*)(ws + O_OFT);
    float2* part = (float2*)(ws + O_PART);

    for (int l = 0; l < 5; l++) {
        k_ydft<<<1024, 256, 0, stream>>>(cur, ws + O_EY, G);
        k_xdft<<<640, 256, 0, stream>>>(G, ws + O_EX, ftT);
        const float2* w1l = (const float2*)(spec_w1 + (size_t)l*13107200);
        const float2* w2l = (const float2*)(spec_w2 + (size_t)l*13107200);
        if (split) {
            k_modemix<<<2048, 448, 0, stream>>>(w1l, w2l, ftT, part, 16);
            k_modered<<<400, 512, 0, stream>>>(part, oft);
        } else {
            k_modemix<<<256, 448, 0, stream>>>(w1l, w2l, ftT, oft, 128);
        }
        k_xidft<<<1024, 256, 0, stream>>>(oft, ws + O_EXI, G);   // T into G
        k_spec_lin<<<2048, 256, 0, stream>>>(cur, G, ws + O_WWT + (size_t)l*16384,
                                             w_b + l*128, nxt, (l < 4) ? 1 : 0);
        float* t = cur; cur = nxt; nxt = t;
    }
    // after 5 layers: cur == ws+O_HB
    k_tail<<<1800, 256, 0, stream>>>(cur, fc1_w, fc1_b, head1_w, head1_b,
                                     head2_w, head2_b, out);
}

// Round 6
// 1717.181 us; speedup vs baseline: 7.7797x; 7.7797x over previous
//
#include <hip/hip_runtime.h>
#include <math.h>

// ---------------- problem constants ----------------
// B=2, S=240, WIDTH=128, M=20, PAD=16 -> padded spatial 256x256
// modes: kx in {0..19} (w1) and {236..255} (w2) -> j=0..39 ; ky in {0..19}

// ---------------- ws layout (float offsets) ----------------
#define SZ_H   (2ull*256*256*128)          // 8,388,608 floats
#define O_HA   0ull
#define O_HB   (O_HA + SZ_H)
#define O_G    (O_HB + SZ_H)               // float2[2*256*20*128]
#define SZ_G   (2ull*256*20*128*2)
#define O_FTT  (O_G + SZ_G)                // float2[128*2*800]
#define SZ_FT  (2ull*40*20*128*2)
#define O_OFT  (O_FTT + SZ_FT)
#define O_EY   (O_OFT + SZ_FT)             // float2[256*20]
#define SZ_EY  (256ull*20*2)
#define O_EX   (O_EY + SZ_EY)              // float2[256*40]
#define SZ_EX  (256ull*40*2)
#define O_EXI  (O_EX + SZ_EX)
#define O_WWT  (O_EXI + SZ_EX)             // 5*128*128 transposed w_w
#define SZ_WWT 81920ull
#define O_PART (O_WWT + SZ_WWT)            // 8 x 204800 float2 partials
#define SZ_PART (8ull*204800*2)

// branchless gelu: erf via Abramowitz-Stegun 7.1.26 (|err| <= 1.5e-7)
static __device__ __forceinline__ float gelu_f(float v) {
    float z  = v * 0.70710678118654752f;
    float az = fabsf(z);
    float t  = __builtin_amdgcn_rcpf(fmaf(0.3275911f, az, 1.0f));
    float p  = fmaf(fmaf(fmaf(fmaf(1.061405429f, t, -1.453152027f), t,
                    1.421413741f), t, -0.284496736f), t, 0.254829592f);
    float e  = __expf(-z * z);
    float er = fmaf(-p * t, e, 1.0f);      // erf(|z|)
    er = copysignf(er, z);
    return 0.5f * v * (1.0f + er);
}

// ---------------- K0: tables + w_w transpose ----------------
__global__ void k_prep(const float* __restrict__ w_w, float* __restrict__ ws) {
    int i = blockIdx.x * 256 + threadIdx.x;
    const float STEP = 6.2831853071795864769f / 256.0f;
    if (i < 5120) {                       // Ey[y][ky] = exp(-2pi i ky y/256)
        int ky = i % 20, y = i / 20;
        int t = (ky * y) & 255;
        float th = t * STEP;
        ws[O_EY + 2*(size_t)i]     = cosf(th);
        ws[O_EY + 2*(size_t)i + 1] = -sinf(th);
    } else if (i < 15360) {               // Ex[x][j] = exp(-2pi i kx x/256)
        int m = i - 5120; int j = m % 40, x = m / 40;
        int kx = (j < 20) ? j : (216 + j);
        int t = (kx * x) & 255;
        float th = t * STEP;
        ws[O_EX + 2*(size_t)m]     = cosf(th);
        ws[O_EX + 2*(size_t)m + 1] = -sinf(th);
    } else if (i < 25600) {               // Exi[x][j] = exp(+2pi i kx x/256)
        int m = i - 15360; int j = m % 40, x = m / 40;
        int kx = (j < 20) ? j : (216 + j);
        int t = (kx * x) & 255;
        float th = t * STEP;
        ws[O_EXI + 2*(size_t)m]     = cosf(th);
        ws[O_EXI + 2*(size_t)m + 1] = sinf(th);
    } else {                              // wwT[l][ic][oc] = w_w[l][oc][ic]
        int m = i - 25600;
        if (m < 81920) {
            int l = m >> 14, r = m & 16383;
            int ic = r >> 7, oc = r & 127;
            ws[O_WWT + m] = w_w[(size_t)l*16384 + oc*128 + ic];
        }
    }
}

// ---------------- K1: fc0 + grid concat + zero-pad (float4) -----------
__global__ __launch_bounds__(256) void k_fc0(const float* __restrict__ xin,
        const float* __restrict__ w, const float* __restrict__ bv,
        float4* __restrict__ H4) {
    size_t e = (size_t)blockIdx.x * 256 + threadIdx.x;   // < 4,194,304
    int c4 = (int)(e & 31) * 4;
    int y = (int)((e >> 5) & 255);
    int x = (int)((e >> 13) & 255);
    int b = (int)(e >> 21);
    float4 h = make_float4(0.f, 0.f, 0.f, 0.f);
    if (x < 240 && y < 240) {
        const float* xp = xin + (((size_t)(b*240 + x))*240 + y)*3;
        float x0 = xp[0], x1 = xp[1], x2 = xp[2];
        float gx = x*(1.0f/239.0f), gy = y*(1.0f/239.0f);
        float4 w0 = *(const float4*)&w[c4];
        float4 w1 = *(const float4*)&w[128 + c4];
        float4 w2 = *(const float4*)&w[256 + c4];
        float4 w3 = *(const float4*)&w[384 + c4];
        float4 w4 = *(const float4*)&w[512 + c4];
        float4 bb = *(const float4*)&bv[c4];
        h.x = bb.x + x0*w0.x + x1*w1.x + x2*w2.x + gx*w3.x + gy*w4.x;
        h.y = bb.y + x0*w0.y + x1*w1.y + x2*w2.y + gx*w3.y + gy*w4.y;
        h.z = bb.z + x0*w0.z + x1*w1.z + x2*w2.z + gx*w3.z + gy*w4.z;
        h.w = bb.w + x0*w0.w + x1*w1.w + x2*w2.w + gx*w3.w + gy*w4.w;
    }
    H4[e] = h;
}

// ---------------- K2: y-DFT  H -> G[b][x][ky][c] ----------------
// grid 1024 = b(2) x x(256) x kh(2): ky split over blocks -> 16 waves/CU
__global__ __launch_bounds__(256) void k_ydft(const float* __restrict__ H,
        const float* __restrict__ Ey, float2* __restrict__ G) {
    int kh = blockIdx.x & 1;
    int x  = (blockIdx.x >> 1) & 255;
    int b  = blockIdx.x >> 9;
    int c = threadIdx.x & 127;
    int yq = __builtin_amdgcn_readfirstlane((int)(threadIdx.x >> 7));  // 0,1
    int k0 = kh * 10;
    const float* Hrow = H + ((size_t)(b*256 + x)) * 256 * 128;
    float ar[10], ai[10];
    #pragma unroll
    for (int k = 0; k < 10; k++) { ar[k] = 0.f; ai[k] = 0.f; }
    #pragma unroll 2
    for (int i = 0; i < 128; i++) {
        int y = yq*128 + i;
        float v = Hrow[(size_t)y*128 + c];
        const float* e = Ey + (size_t)y*40 + k0*2;
        #pragma unroll
        for (int k = 0; k < 10; k++) {
            ar[k] = fmaf(v, e[2*k],   ar[k]);
            ai[k] = fmaf(v, e[2*k+1], ai[k]);
        }
    }
    __shared__ float red[10][128][2];   // 10 KB
    if (yq == 1) {
        #pragma unroll
        for (int k = 0; k < 10; k++) { red[k][c][0] = ar[k]; red[k][c][1] = ai[k]; }
    }
    __syncthreads();
    if (yq == 0) {
        float2* Gp = G + ((size_t)(b*256 + x))*20*128;
        #pragma unroll
        for (int k = 0; k < 10; k++)
            Gp[(k0 + k)*128 + c] = make_float2(ar[k] + red[k][c][0], ai[k] + red[k][c][1]);
    }
}

// ---------------- K3: x-DFT  G -> ftT[ic][b][j*20+ky] ----------------
// 640 blocks. block 256 = xq(8) x cl(32). shfl_xor(32) + 3-slot LDS combine.
__global__ __launch_bounds__(256) void k_xdft(const float2* __restrict__ G,
        const float* __restrict__ Ex, float2* __restrict__ ftT) {
    // grid 640 = ch(4) x jq(4) x ky(20) x b(2)
    int t = blockIdx.x;
    int ch = t & 3, jq = (t >> 2) & 3, ky = (t >> 4) % 20, b = t / 320;
    int cl = threadIdx.x & 31;
    int xq = threadIdx.x >> 5;            // 0..7 (half-wave granularity)
    int c = ch*32 + cl;
    int j0 = jq*10;
    float ar[10], ai[10];
    #pragma unroll
    for (int k = 0; k < 10; k++) { ar[k] = 0.f; ai[k] = 0.f; }
    for (int i = 0; i < 32; i++) {
        int x = xq*32 + i;
        float2 g = G[(((size_t)(b*256 + x))*20 + ky)*128 + c];
        const float2* e2 = (const float2*)(Ex + (size_t)x*80) + j0;
        #pragma unroll
        for (int k = 0; k < 10; k++) {
            float2 e = e2[k];
            ar[k] = fmaf(g.x, e.x, fmaf(-g.y, e.y, ar[k]));
            ai[k] = fmaf(g.x, e.y, fmaf( g.y, e.x, ai[k]));
        }
    }
    // merge xq pairs across half-waves
    #pragma unroll
    for (int k = 0; k < 10; k++) {
        ar[k] += __shfl_xor(ar[k], 32);
        ai[k] += __shfl_xor(ai[k], 32);
    }
    __shared__ float red[3][10][32][2];   // 7.5 KB
    int wid = threadIdx.x >> 6;           // wave 0..3
    int sub = threadIdx.x & 63;
    if (wid > 0 && sub < 32) {
        #pragma unroll
        for (int k = 0; k < 10; k++) { red[wid-1][k][cl][0] = ar[k]; red[wid-1][k][cl][1] = ai[k]; }
    }
    __syncthreads();
    if (wid == 0 && sub < 32) {
        #pragma unroll
        for (int k = 0; k < 10; k++) {
            float rr = ar[k], ii = ai[k];
            #pragma unroll
            for (int q = 0; q < 3; q++) { rr += red[q][k][cl][0]; ii += red[q][k][cl][1]; }
            ftT[((size_t)c*2 + b)*800 + (size_t)(j0 + k)*20 + ky] = make_float2(rr, ii);
        }
    }
}

// ---------------- K4: mode mixing (HBM-heavy einsum, ic-splittable) ----
__global__ __launch_bounds__(448) void k_modemix(const float2* __restrict__ w1,
        const float2* __restrict__ w2, const float2* __restrict__ ftT,
        float2* __restrict__ outp, int ic_per) {
    int bid = blockIdx.x & 255;
    int icq = blockIdx.x >> 8;             // 0 when unsplit
    int oc = bid >> 1;
    int mh = bid & 1;
    int tid = threadIdx.x;
    if (tid >= 400) return;
    int wsel = tid / 200;
    int m = mh*200 + (tid % 200);
    int jk = wsel*400 + m;
    const float2* wb = wsel ? w2 : w1;
    int ic0 = icq * ic_per;
    float ar0=0.f, ai0=0.f, ar1=0.f, ai1=0.f;
    #pragma unroll 8
    for (int i = 0; i < ic_per; i++) {
        int ic = ic0 + i;
        float2 wv = wb[((size_t)(ic*128 + oc))*400 + m];
        float2 f0 = ftT[(size_t)ic*1600 + jk];
        float2 f1 = ftT[(size_t)ic*1600 + 800 + jk];
        ar0 = fmaf(f0.x, wv.x, fmaf(-f0.y, wv.y, ar0));
        ai0 = fmaf(f0.x, wv.y, fmaf( f0.y, wv.x, ai0));
        ar1 = fmaf(f1.x, wv.x, fmaf(-f1.y, wv.y, ar1));
        ai1 = fmaf(f1.x, wv.y, fmaf( f1.y, wv.x, ai1));
    }
    float2* o = outp + (size_t)icq * 204800;
    o[(size_t)jk*128 + oc]         = make_float2(ar0, ai0);
    o[(size_t)(800 + jk)*128 + oc] = make_float2(ar1, ai1);
}

// reduce 8 partials -> oft
__global__ __launch_bounds__(512) void k_modered(const float2* __restrict__ part,
        float2* __restrict__ oft) {
    int i = blockIdx.x * 512 + threadIdx.x;
    if (i >= 204800) return;
    float2 s = part[i];
    #pragma unroll
    for (int q = 1; q < 8; q++) {
        float2 p = part[(size_t)q*204800 + i];
        s.x += p.x; s.y += p.y;
    }
    oft[i] = s;
}

// ---------------- K5: x-IDFT  oft -> T[b][x][ky][oc] (into G buffer) ---
// grid 1024 = b(2) x x(256) x kh(2); block 256 = js(2) x oc(128).
__global__ __launch_bounds__(256) void k_xidft(const float2* __restrict__ oft,
        const float* __restrict__ Exi, float2* __restrict__ T) {
    int kh = blockIdx.x & 1;
    int x  = (blockIdx.x >> 1) & 255;
    int b  = blockIdx.x >> 9;
    int oc = threadIdx.x & 127;
    int js = __builtin_amdgcn_readfirstlane((int)(threadIdx.x >> 7));  // 0,1
    int k0 = kh * 10;
    float ar[10], ai[10];
    #pragma unroll
    for (int k = 0; k < 10; k++) { ar[k] = 0.f; ai[k] = 0.f; }
    const float2* ob = oft + (size_t)b*800*128;
    for (int j = js*20; j < js*20 + 20; j++) {
        float er = Exi[(size_t)x*80 + 2*j], ei = Exi[(size_t)x*80 + 2*j + 1];
        #pragma unroll
        for (int k = 0; k < 10; k++) {
            float2 o = ob[(size_t)(j*20 + k0 + k)*128 + oc];
            ar[k] = fmaf(o.x, er, fmaf(-o.y, ei, ar[k]));
            ai[k] = fmaf(o.x, ei, fmaf( o.y, er, ai[k]));
        }
    }
    __shared__ float red[10][128][2];   // 10 KB
    if (js == 1) {
        #pragma unroll
        for (int k = 0; k < 10; k++) { red[k][oc][0] = ar[k]; red[k][oc][1] = ai[k]; }
    }
    __syncthreads();
    if (js == 0) {
        float2* Tp = T + ((size_t)(b*256 + x))*20*128;
        #pragma unroll
        for (int k = 0; k < 10; k++)
            Tp[(k0 + k)*128 + oc] = make_float2(ar[k] + red[k][oc][0], ai[k] + red[k][oc][1]);
    }
}

// -------- K6: y-IDFT + pointwise linear + bias + gelu ------------------
// R2 geometry: grid 2048 x 256 thr, 64-y tile, hl[64][132].
// Weights/T via s_load bursts (wave-uniform), acts via per-lane ds_read_b128.
__global__ __launch_bounds__(256) void k_spec_lin(const float* __restrict__ H,
        const float2* __restrict__ T, const float* __restrict__ wwT,
        const float* __restrict__ wb, float* __restrict__ Hout, int do_gelu) {
    // grid 2048 = ((b*256)+x)*4 + yg
    int yg = blockIdx.x & 3;
    int x  = (blockIdx.x >> 2) & 255;
    int b  = blockIdx.x >> 10;
    int tid = threadIdx.x;
    int lane = tid & 63;
    int wv = __builtin_amdgcn_readfirstlane(tid >> 6);   // 0..3
    int oc0 = wv * 32;
    int y0 = yg * 64;
    __shared__ __align__(16) float hl[64][132];   // 33.8 KB
    const float* Hbase = H + (((size_t)(b*256 + x))*256 + y0)*128;
    #pragma unroll
    for (int it = 0; it < 8; it++) {
        int i = tid + it*256;                // 2048 float4
        int pi = i >> 5, c4 = (i & 31)*4;
        float4 v = *(const float4*)&Hbase[(size_t)pi*128 + c4];
        *(float4*)&hl[pi][c4] = v;
    }
    __syncthreads();
    float acc[32];
    #pragma unroll
    for (int o = 0; o < 32; o++) acc[o] = 0.f;
    // pointwise linear: batch 16 h-values per lane, then 512-FMA burst
    for (int icb = 0; icb < 128; icb += 16) {
        float tvals[16];
        #pragma unroll
        for (int q = 0; q < 4; q++)
            *(float4*)&tvals[q*4] = *(const float4*)&hl[lane][icb + q*4];
        #pragma unroll
        for (int ii = 0; ii < 16; ii++) {
            float t = tvals[ii];
            const float* wr = &wwT[(size_t)(icb + ii)*128 + oc0];
            #pragma unroll
            for (int o4 = 0; o4 < 8; o4++) {
                float4 w = *(const float4*)&wr[o4*4];
                acc[o4*4]   = fmaf(t, w.x, acc[o4*4]);
                acc[o4*4+1] = fmaf(t, w.y, acc[o4*4+1]);
                acc[o4*4+2] = fmaf(t, w.z, acc[o4*4+2]);
                acc[o4*4+3] = fmaf(t, w.w, acc[o4*4+3]);
            }
        }
    }
    // per-lane trig (f(ky)/65536 folded in) — computed late to shrink live range
    float csr[20], csi[20];
    {
        int y = y0 + lane;
        #pragma unroll
        for (int k = 0; k < 20; k++) {
            int t = (k * y) & 255;
            float th = t * (6.2831853071795864769f/256.0f);
            float f = (k == 0 ? 1.0f : 2.0f) * (1.0f/65536.0f);
            csr[k] = f * __cosf(th);
            csi[k] = f * __sinf(th);
        }
    }
    // spectral: T values wave-uniform (s_load), trig lane-varying
    const float2* Tp = T + ((size_t)(b*256 + x))*20*128 + oc0;
    for (int k = 0; k < 20; k++) {
        const float2* tr = Tp + (size_t)k*128;
        float cr = csr[k], ci = csi[k];
        #pragma unroll
        for (int o = 0; o < 32; o++) {
            float2 tv = tr[o];
            acc[o] = fmaf(tv.x, cr, fmaf(-tv.y, ci, acc[o]));
        }
    }
    __syncthreads();            // all hl reads complete
    const float* bp = &wb[oc0];
    #pragma unroll
    for (int o4 = 0; o4 < 8; o4++) {
        float4 r;
        r.x = acc[o4*4]   + bp[o4*4];
        r.y = acc[o4*4+1] + bp[o4*4+1];
        r.z = acc[o4*4+2] + bp[o4*4+2];
        r.w = acc[o4*4+3] + bp[o4*4+3];
        if (do_gelu) { r.x = gelu_f(r.x); r.y = gelu_f(r.y); r.z = gelu_f(r.z); r.w = gelu_f(r.w); }
        *(float4*)&hl[lane][oc0 + o4*4] = r;   // transpose through LDS
    }
    __syncthreads();
    float* Obase = Hout + (((size_t)(b*256 + x))*256 + y0)*128;
    #pragma unroll
    for (int it = 0; it < 32; it++) {
        int i = tid + it*256;   // 8192 floats
        int pi = i >> 7, c = i & 127;
        Obase[(size_t)pi*128 + c] = hl[pi][c];
    }
}

// ---------------- K7: fused crop + fc1 + gelu + heads ------------------
// R4 version: 128 px/block, 512 thr = 8 waves. One [128][132] LDS tile
// reused (h -> t). phase2: wave -> 16 oc, lane -> px pair. phase3: wave ->
// (head k, px-half): all 64 d in-lane, 64-FMA bursts.
__global__ __launch_bounds__(512) void k_tail(const float* __restrict__ H,
        const float* __restrict__ fc1_w, const float* __restrict__ fc1_b,
        const float* __restrict__ h1w, const float* __restrict__ h1b,
        const float* __restrict__ h2w, const float* __restrict__ h2b,
        float* __restrict__ out) {
    int tid = threadIdx.x;
    int lane = tid & 63;
    int wv = __builtin_amdgcn_readfirstlane(tid >> 6);   // 0..7
    int p0 = blockIdx.x * 128;             // 900 blocks, 128 px each
    __shared__ __align__(16) float hl[128][132];   // 67.6 KB
    // ---- phase 1: load + crop 128 px x 128 c ----
    #pragma unroll
    for (int it = 0; it < 8; it++) {
        int i = tid + it*512;              // 4096 float4
        int pi = i >> 5, c4 = (i & 31)*4;
        int p = p0 + pi;
        int bb = p / 57600, r = p % 57600;
        int xx = r / 240, yy = r % 240;
        float4 v = *(const float4*)&H[(((size_t)(bb*256 + xx))*256 + yy)*128 + c4];
        *(float4*)&hl[pi][c4] = v;
    }
    __syncthreads();
    // ---- phase 2: fc1. wave -> oc slice [wv*16, wv*16+16); lane -> 2 px ----
    int oc0 = wv * 16;
    float acc0[16], acc1[16];
    #pragma unroll
    for (int o = 0; o < 16; o++) { acc0[o] = 0.f; acc1[o] = 0.f; }
    for (int icb = 0; icb < 128; icb += 8) {
        float tv0[8], tv1[8];
        *(float4*)&tv0[0] = *(const float4*)&hl[lane][icb];
        *(float4*)&tv0[4] = *(const float4*)&hl[lane][icb + 4];
        *(float4*)&tv1[0] = *(const float4*)&hl[lane + 64][icb];
        *(float4*)&tv1[4] = *(const float4*)&hl[lane + 64][icb + 4];
        #pragma unroll
        for (int ii = 0; ii < 8; ii++) {
            float t0 = tv0[ii], t1 = tv1[ii];
            const float* wr = &fc1_w[(size_t)(icb + ii)*128 + oc0];
            #pragma unroll
            for (int o4 = 0; o4 < 4; o4++) {
                float4 w = *(const float4*)&wr[o4*4];
                acc0[o4*4]   = fmaf(t0, w.x, acc0[o4*4]);
                acc0[o4*4+1] = fmaf(t0, w.y, acc0[o4*4+1]);
                acc0[o4*4+2] = fmaf(t0, w.z, acc0[o4*4+2]);
                acc0[o4*4+3] = fmaf(t0, w.w, acc0[o4*4+3]);
                acc1[o4*4]   = fmaf(t1, w.x, acc1[o4*4]);
                acc1[o4*4+1] = fmaf(t1, w.y, acc1[o4*4+1]);
                acc1[o4*4+2] = fmaf(t1, w.z, acc1[o4*4+2]);
                acc1[o4*4+3] = fmaf(t1, w.w, acc1[o4*4+3]);
            }
        }
    }
    __syncthreads();                       // all hl reads done before overwrite
    #pragma unroll
    for (int o4 = 0; o4 < 4; o4++) {
        float4 b4 = *(const float4*)&fc1_b[oc0 + o4*4];
        float4 r0, r1;
        r0.x = gelu_f(acc0[o4*4]   + b4.x);
        r0.y = gelu_f(acc0[o4*4+1] + b4.y);
        r0.z = gelu_f(acc0[o4*4+2] + b4.z);
        r0.w = gelu_f(acc0[o4*4+3] + b4.w);
        r1.x = gelu_f(acc1[o4*4]   + b4.x);
        r1.y = gelu_f(acc1[o4*4+1] + b4.y);
        r1.z = gelu_f(acc1[o4*4+2] + b4.z);
        r1.w = gelu_f(acc1[o4*4+3] + b4.w);
        *(float4*)&hl[lane][oc0 + o4*4]      = r0;   // tl[px][oc]
        *(float4*)&hl[lane + 64][oc0 + o4*4] = r1;
    }
    __syncthreads();
    // ---- phase 3: heads. wave -> (k = wv&3, ph = wv>>2); px = ph*64+lane ----
    int k  = wv & 3, ph = wv >> 2;
    int px = ph*64 + lane;
    float a2[64];
    #pragma unroll
    for (int d = 0; d < 64; d++) a2[d] = 0.f;
    const float* wk = h1w + (size_t)k*8192;
    for (int cb = 0; cb < 128; cb += 8) {
        float tv[8];
        *(float4*)&tv[0] = *(const float4*)&hl[px][cb];
        *(float4*)&tv[4] = *(const float4*)&hl[px][cb + 4];
        #pragma unroll
        for (int cc = 0; cc < 8; cc++) {
            float t = tv[cc];
            const float4* wp = (const float4*)&wk[(size_t)(cb + cc)*64];
            #pragma unroll
            for (int d4 = 0; d4 < 16; d4++) {
                float4 w = wp[d4];
                a2[d4*4]   = fmaf(t, w.x, a2[d4*4]);
                a2[d4*4+1] = fmaf(t, w.y, a2[d4*4+1]);
                a2[d4*4+2] = fmaf(t, w.z, a2[d4*4+2]);
                a2[d4*4+3] = fmaf(t, w.w, a2[d4*4+3]);
            }
        }
    }
    float s = 0.f;
    const float* b1 = &h1b[k*64];
    const float* w2 = &h2w[k*64];
    #pragma unroll
    for (int d = 0; d < 64; d++)
        s += gelu_f(a2[d] + b1[d]) * w2[d];
    out[(size_t)k*115200 + p0 + px] = s + h2b[k];
}

// ---------------- launcher ----------------
extern "C" void kernel_launch(void* const* d_in, const int* in_sizes, int n_in,
                              void* d_out, int out_size, void* d_ws, size_t ws_size,
                              hipStream_t stream) {
    const float* x       = (const float*)d_in[0];
    const float* fc0_w   = (const float*)d_in[1];
    const float* fc0_b   = (const float*)d_in[2];
    const float* spec_w1 = (const float*)d_in[3];
    const float* spec_w2 = (const float*)d_in[4];
    const float* w_w     = (const float*)d_in[5];
    const float* w_b     = (const float*)d_in[6];
    const float* fc1_w   = (const float*)d_in[7];
    const float* fc1_b   = (const float*)d_in[8];
    const float* head1_w = (const float*)d_in[9];
    const float* head1_b = (const float*)d_in[10];
    const float* head2_w = (const float*)d_in[11];
    const float* head2_b = (const float*)d_in[12];
    float* ws = (float*)d_ws;
    float* out = (float*)d_out;

    int split = ws_size >= (size_t)(O_PART + SZ_PART) * 4 ? 1 : 0;

    k_prep<<<420, 256, 0, stream>>>(w_w, ws);
    k_fc0<<<16384, 256, 0, stream>>>(x, fc0_w, fc0_b, (float4*)(ws + O_HA));

    float* cur = ws + O_HA;
    float* nxt = ws + O_HB;
    float2* G    = (float2*)(ws + O_G);
    float2* ftT  = (float2*)(ws + O_FTT);
    float2* oft  = (float2*)(ws + O_OFT);
    float2* part = (float2*)(ws + O_PART);

    for (int l = 0; l < 5; l++) {
        k_ydft<<<1024, 256, 0, stream>>>(cur, ws + O_EY, G);
        k_xdft<<<640, 256, 0, stream>>>(G, ws + O_EX, ftT);
        const float2* w1l = (const float2*)(spec_w1 + (size_t)l*13107200);
        const float2* w2l = (const float2*)(spec_w2 + (size_t)l*13107200);
        if (split) {
            k_modemix<<<2048, 448, 0, stream>>>(w1l, w2l, ftT, part, 16);
            k_modered<<<400, 512, 0, stream>>>(part, oft);
        } else {
            k_modemix<<<256, 448, 0, stream>>>(w1l, w2l, ftT, oft, 128);
        }
        k_xidft<<<1024, 256, 0, stream>>>(oft, ws + O_EXI, G);   // T into G
        k_spec_lin<<<2048, 256, 0, stream>>>(cur, G, ws + O_WWT + (size_t)l*16384,
                                             w_b + l*128, nxt, (l < 4) ? 1 : 0);
        float* t = cur; cur = nxt; nxt = t;
    }
    // after 5 layers: cur == ws+O_HB
    k_tail<<<900, 512, 0, stream>>>(cur, fc1_w, fc1_b, head1_w, head1_b,
                                    head2_w, head2_b, out);
}